// Round 17
// baseline (115.554 us; speedup 1.0000x reference)
//
#include <hip/hip_runtime.h>
#include <stdint.h>

#define BS 8192
#define DD 128
#define L2E 1.4426950408889634f
#define LN2 0.6931471805599453f

typedef __attribute__((ext_vector_type(8))) short short8;
typedef __attribute__((ext_vector_type(4))) float float4v;

#if __has_builtin(__builtin_amdgcn_exp2f)
#define EXP2(x) __builtin_amdgcn_exp2f(x)
#else
#define EXP2(x) exp2f(x)
#endif

__device__ __forceinline__ float bf2f(short s) {
  union { unsigned u; float f; } c;
  c.u = ((unsigned)(unsigned short)s) << 16;
  return c.f;
}
__device__ __forceinline__ short f2bf(float f) {
  union { float f; unsigned u; } c; c.f = f;
  unsigned u = c.u + 0x7FFFu + ((c.u >> 16) & 1u);
  return (short)(u >> 16);
}

// Fragment-ordered bf16 layout ("xnbF"): 16-byte chunk index for (row, kc):
//   chunk(row,kc) = (row>>4)*256 + (kc>>2)*64 + (kc&3)*16 + (row&15)
// A wave load F[g*256 + t*64 + lane] gives lane (quad=lane>>4, col=lane&15) the
// 8 bf16 of row g*16+col, k-chunk 4t+quad — the verified mfma_f32_16x16x32_bf16
// A/B fragment layout (rounds 2-16 absmax=0). A 128-col panel is 2048
// CONTIGUOUS chunks -> linear 32KB global_load_lds staging, conflict-free
// lane-contiguous ds_read_b128.
//
// R16 post-mortem: k_main = 40.5us at VGPR 60 with the 16-slab finale (R14's
// 54.6us was the 128-slab finale LOOP, not regalloc). 128-blk k_norm was +1.8
// vs R12's 512-blk -> reverted. Remaining k_main gap vs ~13us pipe floors is
// the 2-phase stall (m233: stage+vmcnt(0)+barrier ~72% of critical path).
// This round halves the barrier count: 128-col tiles (2x32KB LDS, 4 phases of
// 128 MFMAs/wave instead of 8 of 64). Unlike m132's BK=128 regression,
// occupancy does NOT drop: already 2 blocks/CU; 129KB LDS still fits 160KB.

// K1: normalize rows -> xnbF; class column sums -> gh16 (16-way split, chain
// 32); zero accumulators; mask mf. 512 blocks x 16 rows. (R12 verbatim)
__global__ __launch_bounds__(256) void k_norm(const float* __restrict__ data,
                                              const int* __restrict__ label,
                                              char* __restrict__ xnbF,
                                              float* __restrict__ gh16,
                                              float* __restrict__ Zr,
                                              float* __restrict__ Ur,
                                              float* __restrict__ Vr,
                                              float* __restrict__ mf) {
  __shared__ float shg[256];
  int tid = threadIdx.x, wave = tid >> 6, lane = tid & 63;
  int lh = lane & 31, rsel = lane >> 5;
  shg[tid] = 0.f;
  int rowbase = blockIdx.x * 16;
  if (tid < 16) {  // zero this block's accumulator rows (workspace is poisoned)
    int row = rowbase + tid;
    Zr[row] = 0.f; Ur[row] = 0.f; Vr[row] = 0.f;
    mf[row] = (label[row] == 0) ? 1.f : 0.f;
  }
  __syncthreads();

  float a00 = 0.f, a01 = 0.f, a02 = 0.f, a03 = 0.f;  // class-0 column partials
  float a10 = 0.f, a11 = 0.f, a12 = 0.f, a13 = 0.f;  // class-1
#pragma unroll
  for (int it = 0; it < 2; ++it) {
    int row = rowbase + it * 8 + wave * 2 + rsel;
    float4 v = *(const float4*)&data[row * DD + lh * 4];  // 16B/lane coalesced
    float ss = v.x * v.x + v.y * v.y + v.z * v.z + v.w * v.w;
#pragma unroll
    for (int off = 16; off; off >>= 1) ss += __shfl_xor(ss, off);  // 32-lane
    float rn = 1.f / fmaxf(sqrtf(ss), 1e-12f);  // F.normalize eps clamp
    float x0 = v.x * rn, x1 = v.y * rn, x2 = v.z * rn, x3 = v.w * rn;

    unsigned pk0 = (unsigned)(unsigned short)f2bf(x0) |
                   ((unsigned)(unsigned short)f2bf(x1) << 16);
    unsigned pk1 = (unsigned)(unsigned short)f2bf(x2) |
                   ((unsigned)(unsigned short)f2bf(x3) << 16);
    int kc = lh >> 1;
    size_t chunk = (size_t)(row >> 4) * 256 + (size_t)(kc >> 2) * 64 +
                   (size_t)(kc & 3) * 16 + (row & 15);
    *(uint2*)(xnbF + chunk * 16 + (lh & 1) * 8) = make_uint2(pk0, pk1);

    int lab = label[row];  // half-wave uniform
    if (lab == 0) {
      a00 += x0; a01 += x1; a02 += x2; a03 += x3;
    } else {
      a10 += x0; a11 += x1; a12 += x2; a13 += x3;
    }
  }
  int base = lh * 4;
  atomicAdd(&shg[base + 0], a00); atomicAdd(&shg[base + 1], a01);
  atomicAdd(&shg[base + 2], a02); atomicAdd(&shg[base + 3], a03);
  atomicAdd(&shg[128 + base + 0], a10); atomicAdd(&shg[128 + base + 1], a11);
  atomicAdd(&shg[128 + base + 2], a12); atomicAdd(&shg[128 + base + 3], a13);
  __syncthreads();
  // 16-way-split targets: per-address global atomic chain is 512/16 = 32
  atomicAdd(&gh16[(blockIdx.x & 15) * 256 + tid], shg[tid]);
}

// K2: full-matrix Gram-row reductions, 128-col tiles (4 phases) + 16-slab
// ticket finale (the R16-verified fast finale).
__global__ __launch_bounds__(512, 4) void k_main(const short* __restrict__ xnbF,
                                                 const int* __restrict__ label,
                                                 const float* __restrict__ mf,
                                                 const float* __restrict__ scale,
                                                 const float* __restrict__ gh16,
                                                 float* __restrict__ Zr,
                                                 float* __restrict__ Ur,
                                                 float* __restrict__ Vr,
                                                 int* __restrict__ ticket,
                                                 float* __restrict__ out) {
  __shared__ short tile[2][128 * DD];  // 2 x 32KB double buffer
  __shared__ int credu[8];
  __shared__ float fredu[8];
  __shared__ float dred[24];
  __shared__ int lastf;
  int tid = threadIdx.x, wave = tid >> 6, lane = tid & 63;
  int quad = lane >> 4, col = lane & 15;
  int rbI = blockIdx.x >> 4;  // 0..31: 256-row block (8 waves x 32 rows)
  int sl = blockIdx.x & 15;   // 0..15: 512-col slice (4 tiles of 128)
  float se2 = __expf(scale[0]) * L2E;  // exp(scale)*log2(e): log2-domain logits

  const short8* F = (const short8*)xnbF;
  int gA = rbI * 16 + wave * 2;
  short8 af[2][4];
#pragma unroll
  for (int s = 0; s < 2; ++s)
#pragma unroll
    for (int t = 0; t < 4; ++t) {
      short8 a = F[(size_t)(gA + s) * 256 + t * 64 + lane];
#pragma unroll
      for (int i = 0; i < 8; ++i) a[i] = f2bf(bf2f(a[i]) * se2);
      af[s][t] = a;
    }

  float4v Z0 = {0.f,0.f,0.f,0.f}, Z1 = Z0, U0 = Z0, U1 = Z0, V0 = Z0, V1 = Z0;
  int cb4 = sl * 32;  // chunk-group base of this slice (32 groups = 512 cols)

  // Stage one 128-col tile (32KB = 2048 contiguous chunks): 512 thr x 4 x 16B.
#define STAGE(buf, jt)                                                         \
  {                                                                            \
    const char* s_ = (const char*)xnbF +                                       \
                     ((size_t)(cb4 + (jt) * 8) * 256 + tid) * 16;              \
    char* d_ = (char*)tile[buf] + tid * 16;                                    \
    _Pragma("unroll")                                                          \
    for (int p = 0; p < 4; ++p)                                                \
      __builtin_amdgcn_global_load_lds(                                        \
          (const __attribute__((address_space(1))) void*)(uintptr_t)           \
              (s_ + p * 8192),                                                 \
          (__attribute__((address_space(3))) void*)(uintptr_t)(d_ + p * 8192), \
          16, 0, 0);                                                           \
  }

  STAGE(0, 0);
  __syncthreads();  // tile 0 resident

#pragma unroll 1
  for (int jt = 0; jt < 4; ++jt) {
    if (jt < 3) STAGE((jt + 1) & 1, jt + 1);  // in flight over this compute
    const short8* T8 = (const short8*)tile[jt & 1];
    int jcb = sl * 512 + jt * 128;

#define HALFTILE(jo)                                                           \
    {                                                                          \
      short8 b00 = T8[(jo) * 256 + lane];                                      \
      short8 b01 = T8[(jo) * 256 + 64 + lane];                                 \
      short8 b02 = T8[(jo) * 256 + 128 + lane];                                \
      short8 b03 = T8[(jo) * 256 + 192 + lane];                                \
      short8 b10 = T8[(jo + 1) * 256 + lane];                                  \
      short8 b11 = T8[(jo + 1) * 256 + 64 + lane];                             \
      short8 b12 = T8[(jo + 1) * 256 + 128 + lane];                            \
      short8 b13 = T8[(jo + 1) * 256 + 192 + lane];                            \
      float m0 = mf[jcb + (jo) * 16 + col];                                    \
      float m1 = mf[jcb + (jo + 1) * 16 + col];                                \
      float4v c00 = {0.f, 0.f, 0.f, 0.f}, c01 = c00, c10 = c00, c11 = c00;     \
      c00 = __builtin_amdgcn_mfma_f32_16x16x32_bf16(af[0][0], b00, c00, 0,0,0);\
      c01 = __builtin_amdgcn_mfma_f32_16x16x32_bf16(af[1][0], b00, c01, 0,0,0);\
      c10 = __builtin_amdgcn_mfma_f32_16x16x32_bf16(af[0][0], b10, c10, 0,0,0);\
      c11 = __builtin_amdgcn_mfma_f32_16x16x32_bf16(af[1][0], b10, c11, 0,0,0);\
      c00 = __builtin_amdgcn_mfma_f32_16x16x32_bf16(af[0][1], b01, c00, 0,0,0);\
      c01 = __builtin_amdgcn_mfma_f32_16x16x32_bf16(af[1][1], b01, c01, 0,0,0);\
      c10 = __builtin_amdgcn_mfma_f32_16x16x32_bf16(af[0][1], b11, c10, 0,0,0);\
      c11 = __builtin_amdgcn_mfma_f32_16x16x32_bf16(af[1][1], b11, c11, 0,0,0);\
      c00 = __builtin_amdgcn_mfma_f32_16x16x32_bf16(af[0][2], b02, c00, 0,0,0);\
      c01 = __builtin_amdgcn_mfma_f32_16x16x32_bf16(af[1][2], b02, c01, 0,0,0);\
      c10 = __builtin_amdgcn_mfma_f32_16x16x32_bf16(af[0][2], b12, c10, 0,0,0);\
      c11 = __builtin_amdgcn_mfma_f32_16x16x32_bf16(af[1][2], b12, c11, 0,0,0);\
      c00 = __builtin_amdgcn_mfma_f32_16x16x32_bf16(af[0][3], b03, c00, 0,0,0);\
      c01 = __builtin_amdgcn_mfma_f32_16x16x32_bf16(af[1][3], b03, c01, 0,0,0);\
      c10 = __builtin_amdgcn_mfma_f32_16x16x32_bf16(af[0][3], b13, c10, 0,0,0);\
      c11 = __builtin_amdgcn_mfma_f32_16x16x32_bf16(af[1][3], b13, c11, 0,0,0);\
      _Pragma("unroll")                                                        \
      for (int r = 0; r < 4; ++r) { /* C/D: col=lane&15, row=quad*4+r (m89) */ \
        float l, e;                                                            \
        l = c00[r]; e = EXP2(l);  /* log2-domain, |l|<=20.6: fp32-safe */      \
        Z0[r] += e; U0[r] = fmaf(e, l, U0[r]); V0[r] = fmaf(m0, e, V0[r]);     \
        l = c01[r]; e = EXP2(l);                                               \
        Z1[r] += e; U1[r] = fmaf(e, l, U1[r]); V1[r] = fmaf(m0, e, V1[r]);     \
        l = c10[r]; e = EXP2(l);                                               \
        Z0[r] += e; U0[r] = fmaf(e, l, U0[r]); V0[r] = fmaf(m1, e, V0[r]);     \
        l = c11[r]; e = EXP2(l);                                               \
        Z1[r] += e; U1[r] = fmaf(e, l, U1[r]); V1[r] = fmaf(m1, e, V1[r]);     \
      }                                                                        \
    }
    HALFTILE(0)
    HALFTILE(2)
    HALFTILE(4)
    HALFTILE(6)
#undef HALFTILE
    __syncthreads();  // drains stage(jt+1); protects overwritten buffer
  }
#undef STAGE

  // reduce across the 16 column-lanes sharing each output row, then atomics
#define EMIT(s, Zc, Uc, Vc)                                                    \
  {                                                                            \
    _Pragma("unroll")                                                          \
    for (int r = 0; r < 4; ++r) {                                              \
      float z = Zc[r], u = Uc[r], v0 = Vc[r];                                  \
      _Pragma("unroll")                                                        \
      for (int off = 1; off < 16; off <<= 1) {                                 \
        z += __shfl_xor(z, off);                                               \
        u += __shfl_xor(u, off);                                               \
        v0 += __shfl_xor(v0, off);                                             \
      }                                                                        \
      if (col == 0) {                                                          \
        int row = rbI * 256 + wave * 32 + s * 16 + quad * 4 + r;               \
        int lab = label[row];                                                  \
        float v = (lab == 0) ? v0 : (z - v0);                                  \
        atomicAdd(&Zr[row], z);                                                \
        atomicAdd(&Ur[row], u * LN2); /* log2-domain -> nats */                \
        atomicAdd(&Vr[row], v);                                                \
      }                                                                        \
    }                                                                          \
  }
  EMIT(0, Z0, U0, V0)
  EMIT(1, Z1, U1, V1)
#undef EMIT

  // ---- ticket finale: last block computes counts + dots + total loss ----
  __syncthreads();  // all this block's EMIT atomics issued
  if (tid == 0) {
    int t = __hip_atomic_fetch_add(ticket, 1, __ATOMIC_ACQ_REL,
                                   __HIP_MEMORY_SCOPE_AGENT);
    lastf = (t == 511);
  }
  __syncthreads();
  if (!lastf) return;

  // All 512 blocks' device-scope atomics are at the coherence point; gh16 is
  // from the previous kernel (boundary-visible).
  float* hs = (float*)tile;  // reuse LDS: h0 in [0..127], h1 in [128..255]
  if (tid < 256) {
    float h = 0.f;
#pragma unroll
    for (int i = 0; i < 16; ++i) h += gh16[i * 256 + tid];
    hs[tid] = h;
  }
  int c1i = 0;
#pragma unroll
  for (int k = 0; k < 16; ++k) c1i += label[k * 512 + tid];  // coalesced {0,1}
#pragma unroll
  for (int off = 32; off; off >>= 1) c1i += __shfl_xor(c1i, off);
  if (lane == 0) credu[wave] = c1i;
  __syncthreads();  // hs + credu ready
  int c1t = 0;
#pragma unroll
  for (int w = 0; w < 8; ++w) c1t += credu[w];
  float c1 = (float)c1t, c0 = (float)(BS - c1t);

  // 3 dots of the class-sum vectors (threads 0..127, one dim each)
  float p00 = 0.f, p01 = 0.f, p11 = 0.f;
  if (tid < 128) {
    float h0d = hs[tid], h1d = hs[128 + tid];
    p00 = h0d * h0d; p01 = h0d * h1d; p11 = h1d * h1d;
  }
#pragma unroll
  for (int off = 32; off; off >>= 1) {
    p00 += __shfl_xor(p00, off);
    p01 += __shfl_xor(p01, off);
    p11 += __shfl_xor(p11, off);
  }
  if (lane == 0) { dred[wave] = p00; dred[8 + wave] = p01; dred[16 + wave] = p11; }

  // per-row sum: (U - V/c)/Z
  float rc0 = 1.f / c0, rc1 = 1.f / c1;
  float local = 0.f;
#pragma unroll
  for (int k = 0; k < 16; ++k) {
    int row = k * 512 + tid;
    int lab = label[row];
    float Z = __hip_atomic_load(&Zr[row], __ATOMIC_RELAXED, __HIP_MEMORY_SCOPE_AGENT);
    float U = __hip_atomic_load(&Ur[row], __ATOMIC_RELAXED, __HIP_MEMORY_SCOPE_AGENT);
    float V = __hip_atomic_load(&Vr[row], __ATOMIC_RELAXED, __HIP_MEMORY_SCOPE_AGENT);
    local += (U - V * (lab ? rc1 : rc0)) / Z;
  }
#pragma unroll
  for (int off = 32; off; off >>= 1) local += __shfl_xor(local, off);
  if (lane == 0) fredu[wave] = local;
  __syncthreads();
  if (tid == 0) {
    float se = __expf(scale[0]);
    float a0 = __expf(1.f / c0), a1 = __expf(1.f / c1);
    float rZq0 = 1.f / (c0 * a0 + ((float)BS - c0));
    float rZq1 = 1.f / (c1 * a1 + ((float)BS - c1));
    float d00 = dred[0] + dred[1], d01 = dred[8] + dred[9],
          d11 = dred[16] + dred[17];
    float rows = 0.f;
#pragma unroll
    for (int w = 0; w < 8; ++w) rows += fredu[w];
    // Σ loss_i = Σ a/Zq  −  Σ (S+(a−1)T)/Zq  +  Σ (U − V/c)/Z
    //   class sums: Σ_{c0} S = se·h0·(h0+h1) = se·(d00+d01); Σ_{c0} T = se·d00
    float stsum = se * (rZq0 * ((d00 + d01) + (a0 - 1.f) * d00) +
                        rZq1 * ((d01 + d11) + (a1 - 1.f) * d11));
    float total = c0 * a0 * rZq0 + c1 * a1 * rZq1 - stsum + rows;
    out[0] = total * (0.5f / (float)BS);
  }
}

extern "C" void kernel_launch(void* const* d_in, const int* in_sizes, int n_in,
                              void* d_out, int out_size, void* d_ws, size_t ws_size,
                              hipStream_t stream) {
  const float* data = (const float*)d_in[0];
  const float* scale = (const float*)d_in[1];
  const int* label = (const int*)d_in[2];
  char* ws = (char*)d_ws;
  // ws layout (bytes):
  //   0        xnbF bf16 fragment-order [8192*128]   2 MB
  //   2097152  Zr     f32 [8192]
  //   2129920  Ur     f32 [8192]
  //   2162688  Vr     f32 [8192]
  //   2195456  gh16   f32 [16][256]  (16-slab class sums)
  //   2211840  ticket int [1]
  //   2211872  mf     f32 [8192]
  char* xnbF = ws;
  float* Zr = (float*)(ws + 2097152);
  float* Ur = (float*)(ws + 2129920);
  float* Vr = (float*)(ws + 2162688);
  float* gh16 = (float*)(ws + 2195456);
  int* ticket = (int*)(ws + 2211840);
  float* mf = (float*)(ws + 2211872);

  // gh16 + ticket (16388 B); Zr/Ur/Vr/mf zeroed in k_norm; out stored by
  // k_main's last block.
  hipMemsetAsync(ws + 2195456, 0, 16388, stream);

  k_norm<<<512, 256, 0, stream>>>(data, label, xnbF, gh16, Zr, Ur, Vr, mf);
  k_main<<<512, 512, 0, stream>>>((const short*)xnbF, label, mf, scale, gh16,
                                  Zr, Ur, Vr, ticket, (float*)d_out);
}

// Round 18
// 103.211 us; speedup vs baseline: 1.1196x; 1.1196x over previous
//
#include <hip/hip_runtime.h>
#include <stdint.h>

#define BS 8192
#define DD 128
#define L2E 1.4426950408889634f
#define LN2 0.6931471805599453f

typedef __attribute__((ext_vector_type(8))) short short8;
typedef __attribute__((ext_vector_type(4))) float float4v;

#if __has_builtin(__builtin_amdgcn_exp2f)
#define EXP2(x) __builtin_amdgcn_exp2f(x)
#else
#define EXP2(x) exp2f(x)
#endif

__device__ __forceinline__ float bf2f(short s) {
  union { unsigned u; float f; } c;
  c.u = ((unsigned)(unsigned short)s) << 16;
  return c.f;
}
__device__ __forceinline__ short f2bf(float f) {
  union { float f; unsigned u; } c; c.f = f;
  unsigned u = c.u + 0x7FFFu + ((c.u >> 16) & 1u);
  return (short)(u >> 16);
}

// Fragment-ordered bf16 layout ("xnbF"): 16-byte chunk index for (row, kc):
//   chunk(row,kc) = (row>>4)*256 + (kc>>2)*64 + (kc&3)*16 + (row&15)
// A wave load F[g*256 + t*64 + lane] gives lane (quad=lane>>4, col=lane&15) the
// 8 bf16 of row g*16+col, k-chunk 4t+quad — the verified mfma_f32_16x16x32_bf16
// A/B fragment layout (rounds 2-17 absmax=0). A 64-col panel is 1024 CONTIGUOUS
// chunks -> linear 16KB global_load_lds staging, conflict-free ds_read_b128.
//
// FINAL (R18): session settles on the best measured config (102.9us), after
// R17's barrier-halving attempt (128-col tiles) re-spilled (WRITE 33.4MB) and
// fired its falsifier. Ledger: 64-col 2-phase k_main = 40.5us plateau (VGPR
// 60, pure-atomic WRITE 6.16MB); 512-blk gh16 k_norm beats 128-blk; in-kernel
// 16-slab ticket finale beats both a separate launch (+5us) and a 128-slab
// loop (codegen poison, +14us). Harness fill = 41us fixed. This source is
// byte-identical to the 102.9us-verified round-12 submission.

// K1: normalize rows -> xnbF; class column sums -> gh16 (16-way split, chain
// 32); zero accumulators; mask mf. 512 blocks x 16 rows.
__global__ __launch_bounds__(256) void k_norm(const float* __restrict__ data,
                                              const int* __restrict__ label,
                                              char* __restrict__ xnbF,
                                              float* __restrict__ gh16,
                                              float* __restrict__ Zr,
                                              float* __restrict__ Ur,
                                              float* __restrict__ Vr,
                                              float* __restrict__ mf) {
  __shared__ float shg[256];
  int tid = threadIdx.x, wave = tid >> 6, lane = tid & 63;
  int lh = lane & 31, rsel = lane >> 5;
  shg[tid] = 0.f;
  int rowbase = blockIdx.x * 16;
  if (tid < 16) {  // zero this block's accumulator rows (workspace is poisoned)
    int row = rowbase + tid;
    Zr[row] = 0.f; Ur[row] = 0.f; Vr[row] = 0.f;
    mf[row] = (label[row] == 0) ? 1.f : 0.f;
  }
  __syncthreads();

  float a00 = 0.f, a01 = 0.f, a02 = 0.f, a03 = 0.f;  // class-0 column partials
  float a10 = 0.f, a11 = 0.f, a12 = 0.f, a13 = 0.f;  // class-1
#pragma unroll
  for (int it = 0; it < 2; ++it) {
    int row = rowbase + it * 8 + wave * 2 + rsel;
    float4 v = *(const float4*)&data[row * DD + lh * 4];  // 16B/lane coalesced
    float ss = v.x * v.x + v.y * v.y + v.z * v.z + v.w * v.w;
#pragma unroll
    for (int off = 16; off; off >>= 1) ss += __shfl_xor(ss, off);  // 32-lane
    float rn = 1.f / fmaxf(sqrtf(ss), 1e-12f);  // F.normalize eps clamp
    float x0 = v.x * rn, x1 = v.y * rn, x2 = v.z * rn, x3 = v.w * rn;

    unsigned pk0 = (unsigned)(unsigned short)f2bf(x0) |
                   ((unsigned)(unsigned short)f2bf(x1) << 16);
    unsigned pk1 = (unsigned)(unsigned short)f2bf(x2) |
                   ((unsigned)(unsigned short)f2bf(x3) << 16);
    int kc = lh >> 1;
    size_t chunk = (size_t)(row >> 4) * 256 + (size_t)(kc >> 2) * 64 +
                   (size_t)(kc & 3) * 16 + (row & 15);
    *(uint2*)(xnbF + chunk * 16 + (lh & 1) * 8) = make_uint2(pk0, pk1);

    int lab = label[row];  // half-wave uniform
    if (lab == 0) {
      a00 += x0; a01 += x1; a02 += x2; a03 += x3;
    } else {
      a10 += x0; a11 += x1; a12 += x2; a13 += x3;
    }
  }
  int base = lh * 4;  // 8 colliders per LDS address
  atomicAdd(&shg[base + 0], a00); atomicAdd(&shg[base + 1], a01);
  atomicAdd(&shg[base + 2], a02); atomicAdd(&shg[base + 3], a03);
  atomicAdd(&shg[128 + base + 0], a10); atomicAdd(&shg[128 + base + 1], a11);
  atomicAdd(&shg[128 + base + 2], a12); atomicAdd(&shg[128 + base + 3], a13);
  __syncthreads();
  // 16-way-split targets: per-address global atomic chain is 512/16 = 32
  atomicAdd(&gh16[(blockIdx.x & 15) * 256 + tid], shg[tid]);
}

// K2: full-matrix Gram-row reductions (R6 hot loop) + 16-slab ticket finale.
__global__ __launch_bounds__(512, 4) void k_main(const short* __restrict__ xnbF,
                                                 const int* __restrict__ label,
                                                 const float* __restrict__ mf,
                                                 const float* __restrict__ scale,
                                                 const float* __restrict__ gh16,
                                                 float* __restrict__ Zr,
                                                 float* __restrict__ Ur,
                                                 float* __restrict__ Vr,
                                                 int* __restrict__ ticket,
                                                 float* __restrict__ out) {
  __shared__ short tile[2][64 * DD];  // 2 x 16KB double buffer
  __shared__ int credu[8];
  __shared__ float fredu[8];
  __shared__ float dred[24];
  __shared__ int lastf;
  int tid = threadIdx.x, wave = tid >> 6, lane = tid & 63;
  int quad = lane >> 4, col = lane & 15;
  int rbI = blockIdx.x >> 4;  // 0..31: 256-row block (8 waves x 32 rows)
  int sl = blockIdx.x & 15;   // 0..15: 512-col slice (8 tiles of 64)
  float se2 = __expf(scale[0]) * L2E;  // exp(scale)*log2(e): log2-domain logits

  const short8* F = (const short8*)xnbF;
  int gA = rbI * 16 + wave * 2;
  short8 af[2][4];
#pragma unroll
  for (int s = 0; s < 2; ++s)
#pragma unroll
    for (int t = 0; t < 4; ++t) {
      short8 a = F[(size_t)(gA + s) * 256 + t * 64 + lane];
#pragma unroll
      for (int i = 0; i < 8; ++i) a[i] = f2bf(bf2f(a[i]) * se2);
      af[s][t] = a;
    }

  float4v Z0 = {0.f,0.f,0.f,0.f}, Z1 = Z0, U0 = Z0, U1 = Z0, V0 = Z0, V1 = Z0;
  int cb4 = sl * 32;  // chunk-group base of this slice

#define STAGE(buf, jt)                                                         \
  {                                                                            \
    const char* s_ = (const char*)xnbF +                                       \
                     ((size_t)(cb4 + (jt) * 4) * 256 + tid) * 16;              \
    char* d_ = (char*)tile[buf] + tid * 16;                                    \
    __builtin_amdgcn_global_load_lds(                                          \
        (const __attribute__((address_space(1))) void*)(uintptr_t)s_,          \
        (__attribute__((address_space(3))) void*)(uintptr_t)d_, 16, 0, 0);     \
    __builtin_amdgcn_global_load_lds(                                          \
        (const __attribute__((address_space(1))) void*)(uintptr_t)(s_ + 8192), \
        (__attribute__((address_space(3))) void*)(uintptr_t)(d_ + 8192),       \
        16, 0, 0);                                                             \
  }

  STAGE(0, 0);
  __syncthreads();  // tile 0 resident

#pragma unroll 1
  for (int jt = 0; jt < 8; ++jt) {
    if (jt < 7) STAGE((jt + 1) & 1, jt + 1);  // in flight over this compute
    const short8* T8 = (const short8*)tile[jt & 1];
    int jcb = sl * 512 + jt * 64;

#define HALFTILE(jo)                                                           \
    {                                                                          \
      short8 b00 = T8[(jo) * 256 + lane];                                      \
      short8 b01 = T8[(jo) * 256 + 64 + lane];                                 \
      short8 b02 = T8[(jo) * 256 + 128 + lane];                                \
      short8 b03 = T8[(jo) * 256 + 192 + lane];                                \
      short8 b10 = T8[(jo + 1) * 256 + lane];                                  \
      short8 b11 = T8[(jo + 1) * 256 + 64 + lane];                             \
      short8 b12 = T8[(jo + 1) * 256 + 128 + lane];                            \
      short8 b13 = T8[(jo + 1) * 256 + 192 + lane];                            \
      float m0 = mf[jcb + (jo) * 16 + col];                                    \
      float m1 = mf[jcb + (jo + 1) * 16 + col];                                \
      float4v c00 = {0.f, 0.f, 0.f, 0.f}, c01 = c00, c10 = c00, c11 = c00;     \
      c00 = __builtin_amdgcn_mfma_f32_16x16x32_bf16(af[0][0], b00, c00, 0,0,0);\
      c01 = __builtin_amdgcn_mfma_f32_16x16x32_bf16(af[1][0], b00, c01, 0,0,0);\
      c10 = __builtin_amdgcn_mfma_f32_16x16x32_bf16(af[0][0], b10, c10, 0,0,0);\
      c11 = __builtin_amdgcn_mfma_f32_16x16x32_bf16(af[1][0], b10, c11, 0,0,0);\
      c00 = __builtin_amdgcn_mfma_f32_16x16x32_bf16(af[0][1], b01, c00, 0,0,0);\
      c01 = __builtin_amdgcn_mfma_f32_16x16x32_bf16(af[1][1], b01, c01, 0,0,0);\
      c10 = __builtin_amdgcn_mfma_f32_16x16x32_bf16(af[0][1], b11, c10, 0,0,0);\
      c11 = __builtin_amdgcn_mfma_f32_16x16x32_bf16(af[1][1], b11, c11, 0,0,0);\
      c00 = __builtin_amdgcn_mfma_f32_16x16x32_bf16(af[0][2], b02, c00, 0,0,0);\
      c01 = __builtin_amdgcn_mfma_f32_16x16x32_bf16(af[1][2], b02, c01, 0,0,0);\
      c10 = __builtin_amdgcn_mfma_f32_16x16x32_bf16(af[0][2], b12, c10, 0,0,0);\
      c11 = __builtin_amdgcn_mfma_f32_16x16x32_bf16(af[1][2], b12, c11, 0,0,0);\
      c00 = __builtin_amdgcn_mfma_f32_16x16x32_bf16(af[0][3], b03, c00, 0,0,0);\
      c01 = __builtin_amdgcn_mfma_f32_16x16x32_bf16(af[1][3], b03, c01, 0,0,0);\
      c10 = __builtin_amdgcn_mfma_f32_16x16x32_bf16(af[0][3], b13, c10, 0,0,0);\
      c11 = __builtin_amdgcn_mfma_f32_16x16x32_bf16(af[1][3], b13, c11, 0,0,0);\
      _Pragma("unroll")                                                        \
      for (int r = 0; r < 4; ++r) { /* C/D: col=lane&15, row=quad*4+r (m89) */ \
        float l, e;                                                            \
        l = c00[r]; e = EXP2(l);  /* log2-domain, |l|<=20.6: fp32-safe */      \
        Z0[r] += e; U0[r] = fmaf(e, l, U0[r]); V0[r] = fmaf(m0, e, V0[r]);     \
        l = c01[r]; e = EXP2(l);                                               \
        Z1[r] += e; U1[r] = fmaf(e, l, U1[r]); V1[r] = fmaf(m0, e, V1[r]);     \
        l = c10[r]; e = EXP2(l);                                               \
        Z0[r] += e; U0[r] = fmaf(e, l, U0[r]); V0[r] = fmaf(m1, e, V0[r]);     \
        l = c11[r]; e = EXP2(l);                                               \
        Z1[r] += e; U1[r] = fmaf(e, l, U1[r]); V1[r] = fmaf(m1, e, V1[r]);     \
      }                                                                        \
    }
    HALFTILE(0)
    HALFTILE(2)
#undef HALFTILE
    __syncthreads();  // drains stage(jt+1); protects overwritten buffer
  }
#undef STAGE

  // reduce across the 16 column-lanes sharing each output row, then atomics
#define EMIT(s, Zc, Uc, Vc)                                                    \
  {                                                                            \
    _Pragma("unroll")                                                          \
    for (int r = 0; r < 4; ++r) {                                              \
      float z = Zc[r], u = Uc[r], v0 = Vc[r];                                  \
      _Pragma("unroll")                                                        \
      for (int off = 1; off < 16; off <<= 1) {                                 \
        z += __shfl_xor(z, off);                                               \
        u += __shfl_xor(u, off);                                               \
        v0 += __shfl_xor(v0, off);                                             \
      }                                                                        \
      if (col == 0) {                                                          \
        int row = rbI * 256 + wave * 32 + s * 16 + quad * 4 + r;               \
        int lab = label[row];                                                  \
        float v = (lab == 0) ? v0 : (z - v0);                                  \
        atomicAdd(&Zr[row], z);                                                \
        atomicAdd(&Ur[row], u * LN2); /* log2-domain -> nats */                \
        atomicAdd(&Vr[row], v);                                                \
      }                                                                        \
    }                                                                          \
  }
  EMIT(0, Z0, U0, V0)
  EMIT(1, Z1, U1, V1)
#undef EMIT

  // ---- ticket finale: last block computes counts + dots + total loss ----
  __syncthreads();  // all this block's EMIT atomics issued
  if (tid == 0) {
    int t = __hip_atomic_fetch_add(ticket, 1, __ATOMIC_ACQ_REL,
                                   __HIP_MEMORY_SCOPE_AGENT);
    lastf = (t == 511);
  }
  __syncthreads();
  if (!lastf) return;

  // All 512 blocks' device-scope atomics are at the coherence point; gh16 is
  // from the previous kernel (boundary-visible).
  float* hs = (float*)tile;  // reuse LDS: h0 in [0..127], h1 in [128..255]
  if (tid < 256) {
    float h = 0.f;
#pragma unroll
    for (int i = 0; i < 16; ++i) h += gh16[i * 256 + tid];
    hs[tid] = h;
  }
  int c1i = 0;
#pragma unroll
  for (int k = 0; k < 16; ++k) c1i += label[k * 512 + tid];  // coalesced {0,1}
#pragma unroll
  for (int off = 32; off; off >>= 1) c1i += __shfl_xor(c1i, off);
  if (lane == 0) credu[wave] = c1i;
  __syncthreads();  // hs + credu ready
  int c1t = 0;
#pragma unroll
  for (int w = 0; w < 8; ++w) c1t += credu[w];
  float c1 = (float)c1t, c0 = (float)(BS - c1t);

  // 3 dots of the class-sum vectors (threads 0..127, one dim each)
  float p00 = 0.f, p01 = 0.f, p11 = 0.f;
  if (tid < 128) {
    float h0d = hs[tid], h1d = hs[128 + tid];
    p00 = h0d * h0d; p01 = h0d * h1d; p11 = h1d * h1d;
  }
#pragma unroll
  for (int off = 32; off; off >>= 1) {
    p00 += __shfl_xor(p00, off);
    p01 += __shfl_xor(p01, off);
    p11 += __shfl_xor(p11, off);
  }
  if (lane == 0) { dred[wave] = p00; dred[8 + wave] = p01; dred[16 + wave] = p11; }

  // per-row sum: (U - V/c)/Z
  float rc0 = 1.f / c0, rc1 = 1.f / c1;
  float local = 0.f;
#pragma unroll
  for (int k = 0; k < 16; ++k) {
    int row = k * 512 + tid;
    int lab = label[row];
    float Z = __hip_atomic_load(&Zr[row], __ATOMIC_RELAXED, __HIP_MEMORY_SCOPE_AGENT);
    float U = __hip_atomic_load(&Ur[row], __ATOMIC_RELAXED, __HIP_MEMORY_SCOPE_AGENT);
    float V = __hip_atomic_load(&Vr[row], __ATOMIC_RELAXED, __HIP_MEMORY_SCOPE_AGENT);
    local += (U - V * (lab ? rc1 : rc0)) / Z;
  }
#pragma unroll
  for (int off = 32; off; off >>= 1) local += __shfl_xor(local, off);
  if (lane == 0) fredu[wave] = local;
  __syncthreads();
  if (tid == 0) {
    float se = __expf(scale[0]);
    float a0 = __expf(1.f / c0), a1 = __expf(1.f / c1);
    float rZq0 = 1.f / (c0 * a0 + ((float)BS - c0));
    float rZq1 = 1.f / (c1 * a1 + ((float)BS - c1));
    float d00 = dred[0] + dred[1], d01 = dred[8] + dred[9],
          d11 = dred[16] + dred[17];
    float rows = 0.f;
#pragma unroll
    for (int w = 0; w < 8; ++w) rows += fredu[w];
    // Σ loss_i = Σ a/Zq  −  Σ (S+(a−1)T)/Zq  +  Σ (U − V/c)/Z
    //   class sums: Σ_{c0} S = se·h0·(h0+h1) = se·(d00+d01); Σ_{c0} T = se·d00
    float stsum = se * (rZq0 * ((d00 + d01) + (a0 - 1.f) * d00) +
                        rZq1 * ((d01 + d11) + (a1 - 1.f) * d11));
    float total = c0 * a0 * rZq0 + c1 * a1 * rZq1 - stsum + rows;
    out[0] = total * (0.5f / (float)BS);
  }
}

extern "C" void kernel_launch(void* const* d_in, const int* in_sizes, int n_in,
                              void* d_out, int out_size, void* d_ws, size_t ws_size,
                              hipStream_t stream) {
  const float* data = (const float*)d_in[0];
  const float* scale = (const float*)d_in[1];
  const int* label = (const int*)d_in[2];
  char* ws = (char*)d_ws;
  // ws layout (bytes):
  //   0        xnbF bf16 fragment-order [8192*128]   2 MB
  //   2097152  Zr     f32 [8192]
  //   2129920  Ur     f32 [8192]
  //   2162688  Vr     f32 [8192]
  //   2195456  gh16   f32 [16][256]  (16-way split class sums)
  //   2211840  ticket int [1]
  //   2211872  mf     f32 [8192]
  char* xnbF = ws;
  float* Zr = (float*)(ws + 2097152);
  float* Ur = (float*)(ws + 2129920);
  float* Vr = (float*)(ws + 2162688);
  float* gh16 = (float*)(ws + 2195456);
  int* ticket = (int*)(ws + 2211840);
  float* mf = (float*)(ws + 2211872);

  // gh16 + ticket (16388 B); Zr/Ur/Vr/mf zeroed in k_norm; out stored by
  // k_main's last block.
  hipMemsetAsync(ws + 2195456, 0, 16388, stream);

  k_norm<<<512, 256, 0, stream>>>(data, label, xnbF, gh16, Zr, Ur, Vr, mf);
  k_main<<<512, 512, 0, stream>>>((const short*)xnbF, label, mf, scale, gh16,
                                  Zr, Ur, Vr, ticket, (float*)d_out);
}